// Round 3
// baseline (1078.289 us; speedup 1.0000x reference)
//
#include <hip/hip_runtime.h>
#include <hip/hip_bf16.h>

#define HH 512
#define WW 512
#define CC 16
#define HIDN 128
#define HWSZ (HH*WW)
#define NBLK 1024

typedef __attribute__((ext_vector_type(8))) short short8;
typedef __attribute__((ext_vector_type(4))) short short4v;
typedef __attribute__((ext_vector_type(4))) float float4v;

__device__ __forceinline__ short to_bf16(float f){
    __hip_bfloat16 h = __float2bfloat16(f);
    return __builtin_bit_cast(short, h);
}

// One-time: transpose W1 (80,128) -> W1T bf16 [128][96] (k padded 80..95 = 0),
// W2 (128,16) -> W2T bf16 [16][128]. Also zero the grid-barrier counters
// (workspace is poisoned between graph replays, so this must run every launch).
__global__ void __launch_bounds__(256) prep_kernel(
    const float* __restrict__ W1, const float* __restrict__ W2,
    short* __restrict__ w1t, short* __restrict__ w2t,
    unsigned* __restrict__ bar)
{
    int t = blockIdx.x * blockDim.x + threadIdx.x;
    int stride = gridDim.x * blockDim.x;
    for (int idx = t; idx < HIDN*96; idx += stride){
        int n = idx / 96;
        int k = idx - n*96;
        float v = (k < 80) ? W1[k*HIDN + n] : 0.0f;
        w1t[idx] = to_bf16(v);
    }
    for (int idx = t; idx < CC*HIDN; idx += stride){
        int n = idx >> 7;
        int k = idx & 127;
        w2t[idx] = to_bf16(W2[k*CC + n]);
    }
    if (t < 8*32) bar[t] = 0u;   // 8 step-counters, 128B apart
}

#define RSTRIDE 24          // shorts per x-entry in row buffer (48 B, 16B-aligned at ch 0/8)
#define RROW    (68*RSTRIDE) // shorts per row plane

// ---- per-strip body (identical to the verified v2 kernel) ----
// One strip: dst = src + MLP(gather5(src)), channel 0 passthrough.
// 256 threads = 4 waves. Exactly 2 __syncthreads inside.
__device__ __forceinline__ void do_strip(
    const float* __restrict__ src, float* __restrict__ dst,
    const short* __restrict__ w1t, const short* __restrict__ w2t,
    const float* __restrict__ b1, const float bias2,
    short* __restrict__ rows_u, short (*hdn)[136], const int* offB,
    int t, int w, int ln15, int g4, int y, int xs)
{
    const int yu = (y == 0)      ? 0 : (y - 1);
    const int yd = (y == HH - 1) ? 0 : (y + 1);

    // ---- cooperative row stage: float4 loads, 4x4 register transpose, bf16 b64 writes ----
    if (t < 192){
        const int r  = t >> 6;          // 0=center, 1=up, 2=down
        const int l  = t & 63;
        const int q  = l & 15;          // x-quad: global x = xs + 4q + j
        const int cq = l >> 4;          // channel quad: ch = 4cq + i
        const int rowg = (r == 0) ? y : ((r == 1) ? yu : yd);
        const float* base = src + (size_t)rowg * WW + xs + (q << 2);
        float4v f[4];
        #pragma unroll
        for (int i = 0; i < 4; ++i)
            f[i] = *(const float4v*)(base + (size_t)((cq << 2) + i) * HWSZ);
        #pragma unroll
        for (int j = 0; j < 4; ++j){
            short4v v;
            v[0] = to_bf16(f[0][j]); v[1] = to_bf16(f[1][j]);
            v[2] = to_bf16(f[2][j]); v[3] = to_bf16(f[3][j]);
            *(short4v*)&rows_u[r*RROW + ((q << 2) + 1 + j)*RSTRIDE + (cq << 2)] = v;
        }
    } else if (t < 224){
        // center-row halo: x_local 0 (left, clamp) and 65 (right, wrap-to-0 quirk)
        const int c    = (t - 192) & 15;
        const int side = (t - 192) >> 4;
        const int gx   = (side == 0) ? ((xs == 0) ? 0 : xs - 1)
                                     : ((xs + 64 == WW) ? 0 : xs + 64);
        rows_u[(side * 65)*RSTRIDE + c] =
            to_bf16(src[(size_t)c*HWSZ + (size_t)y*WW + gx]);
    }
    __syncthreads();

    // ---- GEMM1 (swapped): D(128hid,64px) = W1T(128,96) . feats^T(96,64) ----
    float4v acc[2][4];
    #pragma unroll
    for (int mt = 0; mt < 2; ++mt)
        #pragma unroll
        for (int nt = 0; nt < 4; ++nt)
            acc[mt][nt] = (float4v){0.f, 0.f, 0.f, 0.f};

    #pragma unroll
    for (int kk = 0; kk < 3; ++kk){
        short8 bfragF[4];
        #pragma unroll
        for (int nt = 0; nt < 4; ++nt)
            bfragF[nt] = *(const short8*)(&rows_u[offB[kk] + nt * (16 * RSTRIDE)]);
        #pragma unroll
        for (int mt = 0; mt < 2; ++mt){
            const int hrow = (((w << 1) + mt) << 4) + ln15;
            short8 afragW = *(const short8*)(w1t + hrow * 96 + (kk << 5) + (g4 << 3));
            #pragma unroll
            for (int nt = 0; nt < 4; ++nt)
                acc[mt][nt] = __builtin_amdgcn_mfma_f32_16x16x32_bf16(
                    afragW, bfragF[nt], acc[mt][nt], 0, 0, 0);
        }
    }

    // epilogue 1: +b1, relu, bf16, packed b64 writes.
    // C/D layout: px = ln15 (col), hid = 16*(2w+mt) + 4*g4 + r (row)
    #pragma unroll
    for (int mt = 0; mt < 2; ++mt){
        const int hbase = (((w << 1) + mt) << 4) + (g4 << 2);
        const float4v bb = *(const float4v*)(b1 + hbase);   // L1-hot, 16B aligned
        #pragma unroll
        for (int nt = 0; nt < 4; ++nt){
            short4v s;
            #pragma unroll
            for (int r = 0; r < 4; ++r){
                float v = acc[mt][nt][r] + bb[r];
                v = v > 0.f ? v : 0.f;
                s[r] = to_bf16(v);
            }
            *(short4v*)&hdn[(nt << 4) + ln15][hbase] = s;
        }
    }
    __syncthreads();

    // ---- GEMM2: delta(64,16) = hdn(64,128) @ W2T^T; wave w -> px rows [16w,16w+16) ----
    const int pxb = (w << 4) + (g4 << 2);
    const size_t gofs = (size_t)ln15 * HWSZ + (size_t)y * WW + xs + pxb;
    const float4v sold = *(const float4v*)(src + gofs);

    float4v acc2 = (float4v){0.f, 0.f, 0.f, 0.f};
    #pragma unroll
    for (int kk = 0; kk < 4; ++kk){
        const int k0 = kk << 5;
        short8 a = *(const short8*)(&hdn[(w << 4) + ln15][k0 + (g4 << 3)]);
        short8 b = *(const short8*)(w2t + ln15 * HIDN + k0 + (g4 << 3));
        acc2 = __builtin_amdgcn_mfma_f32_16x16x32_bf16(a, b, acc2, 0, 0, 0);
    }

    // epilogue 2: direct float4 store; D layout: ch = ln15, px = pxb + r (reg-consecutive).
    float4v outv;
    #pragma unroll
    for (int r = 0; r < 4; ++r){
        const float v = sold[r] + acc2[r] + bias2;
        outv[r] = (ln15 == 0) ? sold[r] : v;     // channel 0 snapshot restore
    }
    *(float4v*)(dst + gofs) = outv;
}

// ---- fused 8-step persistent kernel with hand-rolled grid barrier ----
// 1024 blocks x 256 threads; 4 strips/block/step (strided: strip s handled by
// block s&1023, so row-neighbors s±8 stay on the same XCD -> L2 locality).
// Barrier semantics (per step):
//   __syncthreads (drains vmcnt -> all block stores are in L2)
//   thread0: __threadfence (agent release: buffer_wbl2, cache-wide writeback)
//            relaxed agent atomicAdd on counters[step]
//            spin on agent-scope relaxed load (bypasses stale L1/L2) + s_sleep
//            __threadfence (agent acquire: buffer_inv)
//   __syncthreads
// Per-step counters -> no reset/generation races. prep_kernel zeroes them.
__global__ void __launch_bounds__(256, 4) fused_kernel(
    const float* __restrict__ state, float* __restrict__ B1, float* __restrict__ out,
    const short* __restrict__ w1t, const short* __restrict__ w2t,
    const float* __restrict__ b1, const float* __restrict__ b2,
    unsigned* __restrict__ bar)
{
    __shared__ __align__(16) short rows_u[3*RROW];
    __shared__ __align__(16) short hdn[64][136];

    const int t    = threadIdx.x;
    const int w    = t >> 6;
    const int lane = t & 63;
    const int ln15 = lane & 15;
    const int g4   = lane >> 4;
    const int b    = blockIdx.x;

    // lane-only hoists (strip-independent)
    int offB[3];
    #pragma unroll
    for (int kk = 0; kk < 3; ++kk){
        const int g  = (kk < 2) ? ((kk << 2) + g4) : (8 + (g4 & 1));
        const int n  = g >> 1;
        const int cb = (g & 1) << 3;
        const int r  = (n == 1) ? 1 : ((n == 2) ? 2 : 0);
        const int dx = (n == 3) ? -1 : ((n == 4) ? 1 : 0);
        offB[kk] = r*RROW + (ln15 + 1 + dx)*RSTRIDE + cb;
    }
    const float bias2 = b2[ln15];

    #pragma unroll 1
    for (int step = 0; step < 8; ++step){
        const float* src = (step == 0) ? state : ((step & 1) ? B1 : out);
        float* dst = (step & 1) ? out : B1;  // step0->B1, ..., step7->out

        #pragma unroll 1
        for (int i = 0; i < 4; ++i){
            const int s  = b + (i << 10);   // strip 0..4095
            const int y  = s >> 3;
            const int xs = (s & 7) << 6;
            do_strip(src, dst, w1t, w2t, b1, bias2,
                     rows_u, hdn, offB, t, w, ln15, g4, y, xs);
        }

        if (step < 7){
            __syncthreads();
            if (t == 0){
                __threadfence();   // release: writeback this XCD's L2
                unsigned* ctr = bar + step*32;
                __hip_atomic_fetch_add(ctr, 1u, __ATOMIC_RELAXED,
                                       __HIP_MEMORY_SCOPE_AGENT);
                while (__hip_atomic_load(ctr, __ATOMIC_RELAXED,
                                         __HIP_MEMORY_SCOPE_AGENT) < (unsigned)NBLK)
                    __builtin_amdgcn_s_sleep(2);
                __threadfence();   // acquire: invalidate stale L1/L2
            }
            __syncthreads();
        }
    }
}

// ---- fallback: single-step kernel (proven v2 structure) ----
__global__ void __launch_bounds__(256, 5) step_kernel(
    const float* __restrict__ src, float* __restrict__ dst,
    const short* __restrict__ w1t, const short* __restrict__ w2t,
    const float* __restrict__ b1, const float* __restrict__ b2)
{
    __shared__ __align__(16) short rows_u[3*RROW];
    __shared__ __align__(16) short hdn[64][136];

    const int t    = threadIdx.x;
    const int w    = t >> 6;
    const int lane = t & 63;
    const int ln15 = lane & 15;
    const int g4   = lane >> 4;

    const int bx = blockIdx.x;
    const int y  = bx >> 3;
    const int xs = (bx & 7) << 6;

    int offB[3];
    #pragma unroll
    for (int kk = 0; kk < 3; ++kk){
        const int g  = (kk < 2) ? ((kk << 2) + g4) : (8 + (g4 & 1));
        const int n  = g >> 1;
        const int cb = (g & 1) << 3;
        const int r  = (n == 1) ? 1 : ((n == 2) ? 2 : 0);
        const int dx = (n == 3) ? -1 : ((n == 4) ? 1 : 0);
        offB[kk] = r*RROW + (ln15 + 1 + dx)*RSTRIDE + cb;
    }
    const float bias2 = b2[ln15];

    do_strip(src, dst, w1t, w2t, b1, bias2,
             rows_u, hdn, offB, t, w, ln15, g4, y, xs);
}

extern "C" void kernel_launch(void* const* d_in, const int* in_sizes, int n_in,
                              void* d_out, int out_size, void* d_ws, size_t ws_size,
                              hipStream_t stream)
{
    const float* state = (const float*)d_in[0];
    const float* W1    = (const float*)d_in[1];
    const float* b1p   = (const float*)d_in[2];
    const float* W2    = (const float*)d_in[3];
    const float* b2p   = (const float*)d_in[4];
    // d_in[5] = n_steps (scalar, == 8) -- hardcoded to keep launches static

    float*    B1  = (float*)d_ws;                                   // 16 MB ping buffer
    short*    w1t = (short*)((char*)d_ws + (size_t)HWSZ * CC * 4);  // [128][96] bf16
    short*    w2t = w1t + HIDN * 96;                                // [16][128] bf16
    unsigned* bar = (unsigned*)(w2t + CC * HIDN);                   // [8*32] barrier ctrs
    float*    out = (float*)d_out;

    prep_kernel<<<32, 256, 0, stream>>>(W1, W2, w1t, w2t, bar);

    void* kargs[] = {
        (void*)&state, (void*)&B1, (void*)&out,
        (void*)&w1t, (void*)&w2t, (void*)&b1p, (void*)&b2p, (void*)&bar
    };
    hipError_t err = hipLaunchCooperativeKernel(
        (const void*)fused_kernel, dim3(NBLK), dim3(256), kargs, 0, stream);

    if (err != hipSuccess){
        (void)hipGetLastError();   // clear sticky error, use fallback path
        dim3 grid(HH * (WW / 64));   // 4096 blocks, one 64-pixel row strip each
        step_kernel<<<grid, 256, 0, stream>>>(state, B1, w1t, w2t, b1p, b2p);
        step_kernel<<<grid, 256, 0, stream>>>(B1, out, w1t, w2t, b1p, b2p);
        step_kernel<<<grid, 256, 0, stream>>>(out, B1, w1t, w2t, b1p, b2p);
        step_kernel<<<grid, 256, 0, stream>>>(B1, out, w1t, w2t, b1p, b2p);
        step_kernel<<<grid, 256, 0, stream>>>(out, B1, w1t, w2t, b1p, b2p);
        step_kernel<<<grid, 256, 0, stream>>>(B1, out, w1t, w2t, b1p, b2p);
        step_kernel<<<grid, 256, 0, stream>>>(out, B1, w1t, w2t, b1p, b2p);
        step_kernel<<<grid, 256, 0, stream>>>(B1, out, w1t, w2t, b1p, b2p);
    }
}

// Round 4
// 559.043 us; speedup vs baseline: 1.9288x; 1.9288x over previous
//
#include <hip/hip_runtime.h>
#include <hip/hip_bf16.h>

#define HH 512
#define WW 512
#define CC 16
#define HIDN 128
#define HWSZ (HH*WW)

typedef __attribute__((ext_vector_type(8))) short short8;
typedef __attribute__((ext_vector_type(4))) short short4v;
typedef __attribute__((ext_vector_type(4))) float float4v;
typedef __attribute__((ext_vector_type(2))) float float2v;

__device__ __forceinline__ short to_bf16(float f){
    __hip_bfloat16 h = __float2bfloat16(f);
    return __builtin_bit_cast(short, h);
}

// One-time: transpose W1 (80,128) -> W1T bf16 [128][96] (k padded 80..95 = 0),
// W2 (128,16) -> W2T bf16 [16][128].
__global__ void __launch_bounds__(256) prep_kernel(
    const float* __restrict__ W1, const float* __restrict__ W2,
    short* __restrict__ w1t, short* __restrict__ w2t)
{
    int t = blockIdx.x * blockDim.x + threadIdx.x;
    int stride = gridDim.x * blockDim.x;
    for (int idx = t; idx < HIDN*96; idx += stride){
        int n = idx / 96;
        int k = idx - n*96;
        float v = (k < 80) ? W1[k*HIDN + n] : 0.0f;
        w1t[idx] = to_bf16(v);
    }
    for (int idx = t; idx < CC*HIDN; idx += stride){
        int n = idx >> 7;
        int k = idx & 127;
        w2t[idx] = to_bf16(W2[k*CC + n]);
    }
}

#define RSTRIDE 24           // shorts per x-entry (48 B, 16B-aligned at ch 0/8)
#define RROW    (68*RSTRIDE) // shorts per row plane

// Two fused steps per launch via ghost zones. Phase A computes step-k state
// for rows {up(y), down(y), y} x cols xs-1..xs+64 (66 positions, 5 MFMA
// n-tiles) into LDS rows_u (bf16) + fp32 center copy; phase B is the
// verified single-step pipeline reading rows_u instead of global.
// Numerically identical to two single-step launches.
__global__ void __launch_bounds__(256, 4) step2_kernel(
    const float* __restrict__ src, float* __restrict__ dst,
    const short* __restrict__ w1t, const short* __restrict__ w2t,
    const float* __restrict__ b1, const float* __restrict__ b2)
{
    // rows_s: staging of src rows (68 cols, xl <-> global col xs-2+xl, clamp/wrap)
    // rows_u: step-k state, [slot][xl' = col-(xs-1)][ch], slots 0=center,1=up,2=down
    // hdn   : hidden activations, rows 0..65 (66 positions max)
    // ctr   : fp32 step-k center row (residual base), aliased onto rows_s --
    //         safe: written in the last phase-A pass AFTER its GEMM1 is done
    //         reading rows_s (a __syncthreads separates them).
    __shared__ __align__(16) short rows_s[3*RROW];
    __shared__ __align__(16) short rows_u[3*RROW];
    __shared__ __align__(16) short hdn[66][136];
    float* ctr = (float*)rows_s;
    // total LDS = 9792*2 + 17952 = 37536 B -> 4 blocks/CU

    const int t    = threadIdx.x;
    const int w    = t >> 6;       // wave 0..3
    const int lane = t & 63;
    const int ln15 = lane & 15;
    const int g4   = lane >> 4;

    const int bx = blockIdx.x;
    const int y  = bx >> 3;
    const int xs = (bx & 7) << 6;

    // neighbor rows: minus clamps, plus WRAPS to 0 (reference quirk)
    const int yu = (y == 0)      ? 0 : (y - 1);
    const int yd = (y == HH - 1) ? 0 : (y + 1);

    // per-lane A-operand (feature) base offsets; x-part = ln15+1+dx, tile adds
    // nt*16*RSTRIDE -> staged index p+1+dx for position p = nt*16+ln15.
    // Works for BOTH rows_s (phase A, 68-col staging) and rows_u (phase B).
    int offA[3];
    #pragma unroll
    for (int kk = 0; kk < 3; ++kk){
        const int g  = (kk < 2) ? ((kk << 2) + g4) : (8 + (g4 & 1));
        const int n  = g >> 1;                 // neighbor 0..4
        const int cb = (g & 1) << 3;           // channel base 0 or 8
        const int r  = (n == 1) ? 1 : ((n == 2) ? 2 : 0);
        const int dx = (n == 3) ? -1 : ((n == 4) ? 1 : 0);
        offA[kk] = r*RROW + (ln15 + 1 + dx)*RSTRIDE + cb;
    }
    const float bias2 = b2[ln15];

    // phase-A feature-index exceptions (see derivation in comments):
    // excA: xs==0, position p==0 (col 0): right(0)=1 lives at staged xl=3 not 2.
    // excB: xs==448, position p==65 (wrapped col 0): left(0)=0 lives at xl=66 not 65.
    const int excA = (xs == 0   && ln15 == 0) ? RSTRIDE : 0;            // kk==2, nt==0
    const int excB = (xs == 448 && ln15 == 1 && g4 >= 2) ? RSTRIDE : 0; // kk==1, nt==4

    // ================= PHASE A: 3 passes (up, down, center-last) =============
    #pragma unroll 1
    for (int pass = 0; pass < 3; ++pass){
        const int slot = (pass == 0) ? 1 : ((pass == 1) ? 2 : 0);
        const int gr   = (pass == 0) ? yu : ((pass == 1) ? yd : y);

        // ---- stage src rows {gr, up(gr), down(gr)} x 68 cols into rows_s ----
        if (t < 204){
            const int r3 = (t >= 136) ? 2 : ((t >= 68) ? 1 : 0);
            const int u  = t - r3 * 68;
            const int q  = u >> 2;      // col quad 0..16
            const int cq = u & 3;       // channel quad
            const int rowg = (r3 == 0) ? gr
                           : ((r3 == 1) ? ((gr == 0) ? 0 : gr - 1)
                                        : ((gr == HH - 1) ? 0 : gr + 1));
            const int c0 = xs - 2 + (q << 2);
            float4v f[4];
            if (c0 >= 0 && c0 <= 508){
                // c0 % 4 == 2 -> 8B-aligned: use float2 pairs (dwordx2)
                const float* base = src + (size_t)rowg * WW + c0;
                #pragma unroll
                for (int i = 0; i < 4; ++i){
                    const float* p = base + (size_t)((cq << 2) + i) * HWSZ;
                    float2v lo = *(const float2v*)(p);
                    float2v hi = *(const float2v*)(p + 2);
                    f[i][0] = lo[0]; f[i][1] = lo[1]; f[i][2] = hi[0]; f[i][3] = hi[1];
                }
            } else {
                #pragma unroll
                for (int j = 0; j < 4; ++j){
                    int c = c0 + j;
                    c = (c < 0) ? 0 : ((c >= 512) ? c - 512 : c);  // clamp low, wrap high
                    #pragma unroll
                    for (int i = 0; i < 4; ++i)
                        f[i][j] = src[(size_t)((cq << 2) + i) * HWSZ + (size_t)rowg * WW + c];
                }
            }
            #pragma unroll
            for (int j = 0; j < 4; ++j){
                short4v v;
                v[0] = to_bf16(f[0][j]); v[1] = to_bf16(f[1][j]);
                v[2] = to_bf16(f[2][j]); v[3] = to_bf16(f[3][j]);
                *(short4v*)&rows_s[r3*RROW + ((q << 2) + j)*RSTRIDE + (cq << 2)] = v;
            }
        }
        __syncthreads();

        // ---- GEMM1 (5 px tiles, positions p=0..65 real, 66..79 masked) ----
        float4v acc[2][5];
        #pragma unroll
        for (int mt = 0; mt < 2; ++mt)
            #pragma unroll
            for (int nt = 0; nt < 5; ++nt)
                acc[mt][nt] = (float4v){0.f, 0.f, 0.f, 0.f};

        #pragma unroll
        for (int kk = 0; kk < 3; ++kk){
            short8 bfragF[5];
            #pragma unroll
            for (int nt = 0; nt < 5; ++nt){
                int ao = offA[kk] + nt * (16 * RSTRIDE);
                if (kk == 2 && nt == 0) ao += excA;
                if (kk == 1 && nt == 4) ao += excB;
                bfragF[nt] = *(const short8*)(&rows_s[ao]);
            }
            #pragma unroll
            for (int mt = 0; mt < 2; ++mt){
                const int hrow = (((w << 1) + mt) << 4) + ln15;
                short8 afragW = *(const short8*)(w1t + hrow * 96 + (kk << 5) + (g4 << 3));
                #pragma unroll
                for (int nt = 0; nt < 5; ++nt)
                    acc[mt][nt] = __builtin_amdgcn_mfma_f32_16x16x32_bf16(
                        afragW, bfragF[nt], acc[mt][nt], 0, 0, 0);
            }
        }

        // epi1: +b1, relu, bf16 -> hdn[p][hid]; mask p>65 (tile 4, ln15>=2)
        #pragma unroll
        for (int mt = 0; mt < 2; ++mt){
            const int hbase = (((w << 1) + mt) << 4) + (g4 << 2);
            const float4v bb = *(const float4v*)(b1 + hbase);
            #pragma unroll
            for (int nt = 0; nt < 5; ++nt){
                if (nt == 4 && ln15 >= 2) continue;
                short4v s;
                #pragma unroll
                for (int r = 0; r < 4; ++r){
                    float v = acc[mt][nt][r] + bb[r];
                    v = v > 0.f ? v : 0.f;
                    s[r] = to_bf16(v);
                }
                *(short4v*)&hdn[(nt << 4) + ln15][hbase] = s;
            }
        }
        __syncthreads();

        // ---- GEMM2 (5 px tiles over 4 waves; wave 0 takes tile 4 too) ----
        #pragma unroll 1
        for (int tile = w; tile < 5; tile += 4){
            // tile 4 has only 2 real rows (p=64,65); clamp garbage lanes to
            // valid rows (MFMA D-rows are independent, bad rows masked below)
            const int arow = (tile < 4) ? ((tile << 4) + ln15) : (64 + (ln15 & 1));
            float4v a2 = (float4v){0.f, 0.f, 0.f, 0.f};
            #pragma unroll
            for (int kk = 0; kk < 4; ++kk){
                const int k0 = kk << 5;
                short8 a = *(const short8*)(&hdn[arow][k0 + (g4 << 3)]);
                short8 b = *(const short8*)(w2t + ln15 * HIDN + k0 + (g4 << 3));
                a2 = __builtin_amdgcn_mfma_f32_16x16x32_bf16(a, b, a2, 0, 0, 0);
            }
            // epi2: s_mid = src + delta + b2 (ch0 = src ch0); write bf16 rows_u
            const int pb = (tile << 4) + (g4 << 2);
            #pragma unroll
            for (int r = 0; r < 4; ++r){
                const int p = pb + r;
                int c = xs - 1 + p;
                c = (c < 0) ? 0 : ((c >= 512) ? c - 512 : c);
                const float sold = src[(size_t)ln15 * HWSZ + (size_t)gr * WW + c];
                const float val = (ln15 == 0) ? sold : (sold + a2[r] + bias2);
                if (p <= 65){
                    rows_u[slot * RROW + p * RSTRIDE + ln15] = to_bf16(val);
                    if (slot == 0 && p >= 1 && p <= 64)
                        ctr[((p - 1) << 4) + ln15] = val;   // fp32 residual base
                }
            }
        }
        // next pass's staging touches rows_s only; gemm2A touches hdn/rows_u/ctr
        // -> no extra barrier needed here (next pass's sync1 orders everything)
    }
    __syncthreads();   // publish rows_u + ctr

    // ================= PHASE B: verified single-step pipeline ================
    {
        float4v acc[2][4];
        #pragma unroll
        for (int mt = 0; mt < 2; ++mt)
            #pragma unroll
            for (int nt = 0; nt < 4; ++nt)
                acc[mt][nt] = (float4v){0.f, 0.f, 0.f, 0.f};

        #pragma unroll
        for (int kk = 0; kk < 3; ++kk){
            short8 bfragF[4];
            #pragma unroll
            for (int nt = 0; nt < 4; ++nt)
                bfragF[nt] = *(const short8*)(&rows_u[offA[kk] + nt * (16 * RSTRIDE)]);
            #pragma unroll
            for (int mt = 0; mt < 2; ++mt){
                const int hrow = (((w << 1) + mt) << 4) + ln15;
                short8 afragW = *(const short8*)(w1t + hrow * 96 + (kk << 5) + (g4 << 3));
                #pragma unroll
                for (int nt = 0; nt < 4; ++nt)
                    acc[mt][nt] = __builtin_amdgcn_mfma_f32_16x16x32_bf16(
                        afragW, bfragF[nt], acc[mt][nt], 0, 0, 0);
            }
        }

        #pragma unroll
        for (int mt = 0; mt < 2; ++mt){
            const int hbase = (((w << 1) + mt) << 4) + (g4 << 2);
            const float4v bb = *(const float4v*)(b1 + hbase);
            #pragma unroll
            for (int nt = 0; nt < 4; ++nt){
                short4v s;
                #pragma unroll
                for (int r = 0; r < 4; ++r){
                    float v = acc[mt][nt][r] + bb[r];
                    v = v > 0.f ? v : 0.f;
                    s[r] = to_bf16(v);
                }
                *(short4v*)&hdn[(nt << 4) + ln15][hbase] = s;
            }
        }
    }
    __syncthreads();

    {
        const int pxb = (w << 4) + (g4 << 2);
        const size_t gofs = (size_t)ln15 * HWSZ + (size_t)y * WW + xs + pxb;

        float4v a2 = (float4v){0.f, 0.f, 0.f, 0.f};
        #pragma unroll
        for (int kk = 0; kk < 4; ++kk){
            const int k0 = kk << 5;
            short8 a = *(const short8*)(&hdn[(w << 4) + ln15][k0 + (g4 << 3)]);
            short8 b = *(const short8*)(w2t + ln15 * HIDN + k0 + (g4 << 3));
            a2 = __builtin_amdgcn_mfma_f32_16x16x32_bf16(a, b, a2, 0, 0, 0);
        }

        float4v outv;
        #pragma unroll
        for (int r = 0; r < 4; ++r){
            const float sold = ctr[((pxb + r) << 4) + ln15];   // fp32 s_mid
            const float v = sold + a2[r] + bias2;
            outv[r] = (ln15 == 0) ? sold : v;   // ch0 = s_mid ch0 = original ch0
        }
        *(float4v*)(dst + gofs) = outv;
    }
}

extern "C" void kernel_launch(void* const* d_in, const int* in_sizes, int n_in,
                              void* d_out, int out_size, void* d_ws, size_t ws_size,
                              hipStream_t stream)
{
    const float* state = (const float*)d_in[0];
    const float* W1    = (const float*)d_in[1];
    const float* b1p   = (const float*)d_in[2];
    const float* W2    = (const float*)d_in[3];
    const float* b2p   = (const float*)d_in[4];
    // d_in[5] = n_steps (scalar, == 8) -- hardcoded to keep launches static

    float* B1  = (float*)d_ws;                                   // 16 MB ping buffer
    short* w1t = (short*)((char*)d_ws + (size_t)HWSZ * CC * 4);  // [128][96] bf16
    short* w2t = w1t + HIDN * 96;                                // [16][128] bf16
    float* out = (float*)d_out;

    prep_kernel<<<32, 256, 0, stream>>>(W1, W2, w1t, w2t);

    dim3 grid(HH * (WW / 64));   // 4096 blocks, one 64-pixel row strip each
    // 4 launches x 2 fused steps = 8 steps
    step2_kernel<<<grid, 256, 0, stream>>>(state, B1, w1t, w2t, b1p, b2p);
    step2_kernel<<<grid, 256, 0, stream>>>(B1, out, w1t, w2t, b1p, b2p);
    step2_kernel<<<grid, 256, 0, stream>>>(out, B1, w1t, w2t, b1p, b2p);
    step2_kernel<<<grid, 256, 0, stream>>>(B1, out, w1t, w2t, b1p, b2p);
}

// Round 5
// 329.717 us; speedup vs baseline: 3.2704x; 1.6955x over previous
//
#include <hip/hip_runtime.h>
#include <hip/hip_bf16.h>

#define HH 512
#define WW 512
#define CC 16
#define HIDN 128
#define HWSZ (HH*WW)

typedef __attribute__((ext_vector_type(8))) short short8;
typedef __attribute__((ext_vector_type(4))) short short4v;
typedef __attribute__((ext_vector_type(4))) float float4v;

__device__ __forceinline__ short to_bf16(float f){
    __hip_bfloat16 h = __float2bfloat16(f);
    return __builtin_bit_cast(short, h);
}

// One-time: transpose W1 (80,128) -> W1T bf16 [128][96] (k padded 80..95 = 0),
// W2 (128,16) -> W2T bf16 [16][128].
__global__ void __launch_bounds__(256) prep_kernel(
    const float* __restrict__ W1, const float* __restrict__ W2,
    short* __restrict__ w1t, short* __restrict__ w2t)
{
    int t = blockIdx.x * blockDim.x + threadIdx.x;
    int stride = gridDim.x * blockDim.x;
    for (int idx = t; idx < HIDN*96; idx += stride){
        int n = idx / 96;
        int k = idx - n*96;
        float v = (k < 80) ? W1[k*HIDN + n] : 0.0f;
        w1t[idx] = to_bf16(v);
    }
    for (int idx = t; idx < CC*HIDN; idx += stride){
        int n = idx >> 7;
        int k = idx & 127;
        w2t[idx] = to_bf16(W2[k*CC + n]);
    }
}

#define RSTRIDE 24           // shorts per x-entry (48 B, 16B-aligned at ch 0/8)
#define RROW    (68*RSTRIDE) // shorts per row plane

// ---- staging split into issue (global->reg) and write (reg->LDS) ----
// so unit u+1's loads can be issued during unit u's compute (T14).
__device__ __forceinline__ void stage_load(
    const float* __restrict__ src, int t, int y, int yu, int yd, int xs,
    float4v f[4], float* halo)
{
    if (t < 192){
        const int r  = t >> 6;          // 0=center, 1=up, 2=down
        const int l  = t & 63;
        const int q  = l & 15;          // x-quad: global x = xs + 4q + j
        const int cq = l >> 4;          // channel quad: ch = 4cq + i
        const int rowg = (r == 0) ? y : ((r == 1) ? yu : yd);
        const float* base = src + (size_t)rowg * WW + xs + (q << 2);
        #pragma unroll
        for (int i = 0; i < 4; ++i)
            f[i] = *(const float4v*)(base + (size_t)((cq << 2) + i) * HWSZ);
    } else if (t < 224){
        // center-row halo: x_local 0 (left, clamp) and 65 (right, wrap-to-0 quirk)
        const int c    = (t - 192) & 15;
        const int side = (t - 192) >> 4;
        const int gx   = (side == 0) ? ((xs == 0) ? 0 : xs - 1)
                                     : ((xs + 64 == WW) ? 0 : xs + 64);
        *halo = src[(size_t)c * HWSZ + (size_t)y * WW + gx];
    }
}

__device__ __forceinline__ void stage_write(
    short* __restrict__ rows_u, int t, const float4v f[4], float halo)
{
    if (t < 192){
        const int r  = t >> 6;
        const int l  = t & 63;
        const int q  = l & 15;
        const int cq = l >> 4;
        #pragma unroll
        for (int j = 0; j < 4; ++j){
            short4v v;
            v[0] = to_bf16(f[0][j]); v[1] = to_bf16(f[1][j]);
            v[2] = to_bf16(f[2][j]); v[3] = to_bf16(f[3][j]);
            *(short4v*)&rows_u[r*RROW + ((q << 2) + 1 + j)*RSTRIDE + (cq << 2)] = v;
        }
    } else if (t < 224){
        const int c    = (t - 192) & 15;
        const int side = (t - 192) >> 4;
        rows_u[(side * 65)*RSTRIDE + c] = to_bf16(halo);
    }
}

// One step for 4 strip-units per block. 1024 blocks -> 4 blocks/CU, ALL
// RESIDENT (one generation). Unit u+1's staging loads issued under unit u's
// GEMMs; sold (residual) prefetched under GEMM1. Body per unit is the
// verified v2 pipeline (2 barriers/unit).
__global__ void __launch_bounds__(256, 5) step_kernel(
    const float* __restrict__ src, float* __restrict__ dst,
    const short* __restrict__ w1t, const short* __restrict__ w2t,
    const float* __restrict__ b1, const float* __restrict__ b2)
{
    __shared__ __align__(16) short rows_u[3*RROW];
    __shared__ __align__(16) short hdn[64][136];   // [px][hid]

    const int t    = threadIdx.x;
    const int w    = t >> 6;       // wave 0..3
    const int lane = t & 63;
    const int ln15 = lane & 15;
    const int g4   = lane >> 4;

    // XCD-bijective swizzle (1024 % 8 == 0): vb's high 3 bits = XCD id ->
    // each XCD owns a contiguous 64-row band; halo rows stay on-die.
    const int b  = blockIdx.x;
    const int vb = ((b & 7) << 7) | (b >> 3);      // 0..1023
    const int y  = vb >> 1;                        // same row for all 4 units
    const int xs0 = ((vb & 1) << 2) << 6;          // 0 or 256; units add u*64

    // neighbor rows: minus clamps, plus WRAPS to 0 (reference quirk)
    const int yu = (y == 0)      ? 0 : (y - 1);
    const int yd = (y == HH - 1) ? 0 : (y + 1);

    // per-lane B-fragment (feats) base offsets
    // feature order k: [center 0-15 | up 16-31 | down 32-47 | left 48-63 | right 64-79]
    // kk==2: only groups 8,9 real; g4>=2 reads finite garbage, annihilated by
    // w1t zero pad at k>=80.
    int offB[3];
    #pragma unroll
    for (int kk = 0; kk < 3; ++kk){
        const int g  = (kk < 2) ? ((kk << 2) + g4) : (8 + (g4 & 1));
        const int n  = g >> 1;                 // neighbor 0..4
        const int cb = (g & 1) << 3;           // channel base 0 or 8
        const int r  = (n == 1) ? 1 : ((n == 2) ? 2 : 0);
        const int dx = (n == 3) ? -1 : ((n == 4) ? 1 : 0);
        offB[kk] = r*RROW + (ln15 + 1 + dx)*RSTRIDE + cb;
    }
    const float bias2 = b2[ln15];

    // prefetch unit 0's staging
    float4v pf[4];
    float   ph = 0.f;
    stage_load(src, t, y, yu, yd, xs0, pf, &ph);

    #pragma unroll 1
    for (int u = 0; u < 4; ++u){
        const int xs = xs0 + (u << 6);

        // LDS fill from prefetched regs (vmcnt wait lands here)
        stage_write(rows_u, t, pf, ph);
        __syncthreads();

        // issue next unit's staging loads NOW -- they complete under the GEMMs
        if (u < 3)
            stage_load(src, t, y, yu, yd, xs + 64, pf, &ph);

        // prefetch residual base for this unit (consumed after GEMM2)
        const int pxb = (w << 4) + (g4 << 2);
        const size_t gofs = (size_t)ln15 * HWSZ + (size_t)y * WW + xs + pxb;
        const float4v sold = *(const float4v*)(src + gofs);

        // ---- GEMM1 (swapped): D(128hid,64px) = W1T(128,96) . feats^T(96,64) ----
        float4v acc[2][4];
        #pragma unroll
        for (int mt = 0; mt < 2; ++mt)
            #pragma unroll
            for (int nt = 0; nt < 4; ++nt)
                acc[mt][nt] = (float4v){0.f, 0.f, 0.f, 0.f};

        #pragma unroll
        for (int kk = 0; kk < 3; ++kk){
            short8 bfragF[4];
            #pragma unroll
            for (int nt = 0; nt < 4; ++nt)
                bfragF[nt] = *(const short8*)(&rows_u[offB[kk] + nt * (16 * RSTRIDE)]);
            #pragma unroll
            for (int mt = 0; mt < 2; ++mt){
                const int hrow = (((w << 1) + mt) << 4) + ln15;
                short8 afragW = *(const short8*)(w1t + hrow * 96 + (kk << 5) + (g4 << 3));
                #pragma unroll
                for (int nt = 0; nt < 4; ++nt)
                    acc[mt][nt] = __builtin_amdgcn_mfma_f32_16x16x32_bf16(
                        afragW, bfragF[nt], acc[mt][nt], 0, 0, 0);
            }
        }

        // epilogue 1: +b1, relu, bf16, packed b64 writes.
        // C/D layout: px = ln15 (col), hid = 16*(2w+mt) + 4*g4 + r (row)
        #pragma unroll
        for (int mt = 0; mt < 2; ++mt){
            const int hbase = (((w << 1) + mt) << 4) + (g4 << 2);
            const float4v bb = *(const float4v*)(b1 + hbase);   // L1-hot
            #pragma unroll
            for (int nt = 0; nt < 4; ++nt){
                short4v s;
                #pragma unroll
                for (int r = 0; r < 4; ++r){
                    float v = acc[mt][nt][r] + bb[r];
                    v = v > 0.f ? v : 0.f;
                    s[r] = to_bf16(v);
                }
                *(short4v*)&hdn[(nt << 4) + ln15][hbase] = s;
            }
        }
        __syncthreads();
        // (rows_u is free from here: all GEMM1 reads are before this barrier.
        //  Next iteration's stage_write happens after it in program order, and
        //  hdn reads below never alias rows_u.)

        // ---- GEMM2: delta(64,16) = hdn(64,128) @ W2T^T; wave w -> px [16w,16w+16) ----
        float4v acc2 = (float4v){0.f, 0.f, 0.f, 0.f};
        #pragma unroll
        for (int kk = 0; kk < 4; ++kk){
            const int k0 = kk << 5;
            short8 a = *(const short8*)(&hdn[(w << 4) + ln15][k0 + (g4 << 3)]);
            short8 bfr = *(const short8*)(w2t + ln15 * HIDN + k0 + (g4 << 3));
            acc2 = __builtin_amdgcn_mfma_f32_16x16x32_bf16(a, bfr, acc2, 0, 0, 0);
        }

        // epilogue 2: direct float4 store; D layout: ch = ln15, px = pxb + r
        float4v outv;
        #pragma unroll
        for (int r = 0; r < 4; ++r){
            const float v = sold[r] + acc2[r] + bias2;
            outv[r] = (ln15 == 0) ? sold[r] : v;     // channel 0 snapshot restore
        }
        *(float4v*)(dst + gofs) = outv;
    }
}

extern "C" void kernel_launch(void* const* d_in, const int* in_sizes, int n_in,
                              void* d_out, int out_size, void* d_ws, size_t ws_size,
                              hipStream_t stream)
{
    const float* state = (const float*)d_in[0];
    const float* W1    = (const float*)d_in[1];
    const float* b1p   = (const float*)d_in[2];
    const float* W2    = (const float*)d_in[3];
    const float* b2p   = (const float*)d_in[4];
    // d_in[5] = n_steps (scalar, == 8) -- hardcoded to keep launches static

    float* B1  = (float*)d_ws;                                   // 16 MB ping buffer
    short* w1t = (short*)((char*)d_ws + (size_t)HWSZ * CC * 4);  // [128][96] bf16
    short* w2t = w1t + HIDN * 96;                                // [16][128] bf16
    float* out = (float*)d_out;

    prep_kernel<<<32, 256, 0, stream>>>(W1, W2, w1t, w2t);

    dim3 grid(1024);   // 4 strip-units per block, all blocks resident
    step_kernel<<<grid, 256, 0, stream>>>(state, B1, w1t, w2t, b1p, b2p);
    step_kernel<<<grid, 256, 0, stream>>>(B1, out, w1t, w2t, b1p, b2p);
    step_kernel<<<grid, 256, 0, stream>>>(out, B1, w1t, w2t, b1p, b2p);
    step_kernel<<<grid, 256, 0, stream>>>(B1, out, w1t, w2t, b1p, b2p);
    step_kernel<<<grid, 256, 0, stream>>>(out, B1, w1t, w2t, b1p, b2p);
    step_kernel<<<grid, 256, 0, stream>>>(B1, out, w1t, w2t, b1p, b2p);
    step_kernel<<<grid, 256, 0, stream>>>(out, B1, w1t, w2t, b1p, b2p);
    step_kernel<<<grid, 256, 0, stream>>>(B1, out, w1t, w2t, b1p, b2p);
}